// Round 1
// baseline (10538.966 us; speedup 1.0000x reference)
//
#include <hip/hip_runtime.h>
#include <cstdint>

#define Hh 64
#define Tt 512
#define Dd 6
#define BB 2   // batch rows per block

__device__ __forceinline__ float sigm(float v){
  return __builtin_amdgcn_rcpf(1.f + __expf(-v));
}
__device__ __forceinline__ float tanh_(float v){
  // 1 - 2/(e^{2v}+1); stable for |v| large (inf -> rcp -> 0)
  return 1.f - 2.f*__builtin_amdgcn_rcpf(1.f + __expf(2.f*v));
}

__global__ __launch_bounds__(256, 2)
void lstm2_head(const float* __restrict__ x,
                const float* __restrict__ Wih0, const float* __restrict__ Whh0,
                const float* __restrict__ bih0, const float* __restrict__ bhh0,
                const float* __restrict__ Wih1, const float* __restrict__ Whh1,
                const float* __restrict__ bih1, const float* __restrict__ bhh1,
                const float* __restrict__ W1, const float* __restrict__ b1,
                const float* __restrict__ W2, const float* __restrict__ b2,
                float* __restrict__ out)
{
  __shared__ __align__(16) float xs[BB][Tt*Dd];     // 24 KB
  __shared__ __align__(16) float h0s[BB][Hh];
  __shared__ __align__(16) float h1s[BB][Hh];
  __shared__ __align__(16) float act0[BB][4][Hh];   // i,f,g,o
  __shared__ __align__(16) float act1[BB][4][Hh];
  __shared__ float zs[BB][32];

  const int tid = threadIdx.x;
  const int b0  = blockIdx.x * BB;
  const int gt  = tid >> 6;          // gate type 0..3 (i,f,g,o) — uniform per wave
  const int gj  = tid & 63;
  const int uj  = tid & 63;          // state-update mapping
  const int ubs = (tid >> 6) & 1;
  const int ulay= tid >> 7;

  // stage x for this block's 2 batch rows (coalesced, 6144 floats)
  {
    const float* gx = x + (size_t)b0 * (Tt*Dd);
    float* xf = &xs[0][0];
    for (int i = tid; i < BB*Tt*Dd; i += 256) xf[i] = gx[i];
  }
  if (tid < BB*Hh) { (&h0s[0][0])[tid] = 0.f; (&h1s[0][0])[tid] = 0.f; }

  // per-thread weight rows in registers (gate row = tid)
  float wih0r[Dd], whh0r[Hh], wih1r[Hh], whh1r[Hh];
  #pragma unroll
  for (int d=0; d<Dd; ++d) wih0r[d] = Wih0[tid*Dd + d];
  #pragma unroll
  for (int j=0; j<Hh; ++j) whh0r[j] = Whh0[tid*Hh + j];
  #pragma unroll
  for (int j=0; j<Hh; ++j) wih1r[j] = Wih1[tid*Hh + j];
  #pragma unroll
  for (int j=0; j<Hh; ++j) whh1r[j] = Whh1[tid*Hh + j];
  const float bias0 = bih0[tid] + bhh0[tid];
  const float bias1 = bih1[tid] + bhh1[tid];

  float creg = 0.f;   // cell state for (ulay, ubs, uj)

  __syncthreads();

  // A(0): layer-0 gates at t=0 (h0 == 0, so just bias + x-projection)
  {
    #pragma unroll
    for (int bs=0; bs<BB; ++bs){
      float acc = bias0;
      #pragma unroll
      for (int d=0; d<Dd; ++d) acc += wih0r[d]*xs[bs][d];
      act0[bs][gt][gj] = (gt==2) ? tanh_(acc) : sigm(acc);
    }
  }
  __syncthreads();
  // B(0): layer-0 state update -> h0(0)
  if (ulay == 0){
    float iv = act0[ubs][0][uj], fv = act0[ubs][1][uj],
          gv = act0[ubs][2][uj], ov = act0[ubs][3][uj];
    creg = fv*creg + iv*gv;
    h0s[ubs][uj] = ov * tanh_(creg);
  }
  __syncthreads();

  // steady state: entering iter t: h0s=h0(t), h1s=h1(t-1)
  // phase CA: act1(t) from {h0(t),h1(t-1)}, act0(t+1) from {h0(t), x(t+1)}
  // phase DB: h1s<-h1(t), h0s<-h0(t+1)
  #pragma unroll 1
  for (int t=0; t<Tt; ++t){
    const bool withA = (t < Tt-1);

    float a1[BB], a0[BB];
    #pragma unroll
    for (int bs=0; bs<BB; ++bs){
      a1[bs] = bias1;
      float acc = bias0;
      if (withA){
        #pragma unroll
        for (int d=0; d<Dd; ++d) acc += wih0r[d]*xs[bs][(t+1)*Dd + d];
      }
      a0[bs] = acc;
    }
    #pragma unroll
    for (int jj=0; jj<Hh; jj+=4){
      #pragma unroll
      for (int bs=0; bs<BB; ++bs){
        const float4 h0v = *(const float4*)&h0s[bs][jj];   // broadcast read
        const float4 h1v = *(const float4*)&h1s[bs][jj];
        a1[bs] += wih1r[jj+0]*h0v.x + wih1r[jj+1]*h0v.y
                + wih1r[jj+2]*h0v.z + wih1r[jj+3]*h0v.w;
        a1[bs] += whh1r[jj+0]*h1v.x + whh1r[jj+1]*h1v.y
                + whh1r[jj+2]*h1v.z + whh1r[jj+3]*h1v.w;
        a0[bs] += whh0r[jj+0]*h0v.x + whh0r[jj+1]*h0v.y
                + whh0r[jj+2]*h0v.z + whh0r[jj+3]*h0v.w;
      }
    }
    #pragma unroll
    for (int bs=0; bs<BB; ++bs){
      act1[bs][gt][gj] = (gt==2) ? tanh_(a1[bs]) : sigm(a1[bs]);
      if (withA)
        act0[bs][gt][gj] = (gt==2) ? tanh_(a0[bs]) : sigm(a0[bs]);
    }
    __syncthreads();

    if (ulay == 1){
      float iv = act1[ubs][0][uj], fv = act1[ubs][1][uj],
            gv = act1[ubs][2][uj], ov = act1[ubs][3][uj];
      creg = fv*creg + iv*gv;
      h1s[ubs][uj] = ov * tanh_(creg);
    } else if (withA){
      float iv = act0[ubs][0][uj], fv = act0[ubs][1][uj],
            gv = act0[ubs][2][uj], ov = act0[ubs][3][uj];
      creg = fv*creg + iv*gv;
      h0s[ubs][uj] = ov * tanh_(creg);
    }
    __syncthreads();
  }

  // MLP head on h1(T-1): z = relu(h1 @ W1.T + b1); out = sigm(z @ W2.T + b2)
  if (tid < BB*32){
    const int bs = tid >> 5, m = tid & 31;
    float acc = b1[m];
    #pragma unroll
    for (int j=0; j<Hh; ++j) acc += W1[m*Hh + j] * h1s[bs][j];
    zs[bs][m] = fmaxf(acc, 0.f);
  }
  __syncthreads();
  if (tid < BB){
    float acc = b2[0];
    #pragma unroll
    for (int m=0; m<32; ++m) acc += W2[m] * zs[tid][m];
    out[b0 + tid] = sigm(acc);
  }
}

extern "C" void kernel_launch(void* const* d_in, const int* in_sizes, int n_in,
                              void* d_out, int out_size, void* d_ws, size_t ws_size,
                              hipStream_t stream) {
  const float* x    = (const float*)d_in[0];
  const float* Wih0 = (const float*)d_in[1];
  const float* Whh0 = (const float*)d_in[2];
  const float* bih0 = (const float*)d_in[3];
  const float* bhh0 = (const float*)d_in[4];
  const float* Wih1 = (const float*)d_in[5];
  const float* Whh1 = (const float*)d_in[6];
  const float* bih1 = (const float*)d_in[7];
  const float* bhh1 = (const float*)d_in[8];
  const float* W1   = (const float*)d_in[9];
  const float* b1   = (const float*)d_in[10];
  const float* W2   = (const float*)d_in[11];
  const float* b2   = (const float*)d_in[12];

  const int B = in_sizes[0] / (Tt*Dd);   // 1024
  dim3 grid(B / BB), block(256);
  hipLaunchKernelGGL(lstm2_head, grid, block, 0, stream,
                     x, Wih0, Whh0, bih0, bhh0, Wih1, Whh1, bih1, bhh1,
                     W1, b1, W2, b2, (float*)d_out);
}

// Round 2
// 1389.372 us; speedup vs baseline: 7.5854x; 7.5854x over previous
//
#include <hip/hip_runtime.h>
#include <cstdint>

#define Hh 64
#define Tt 512
#define Dd 6
#define BB 4      // batch rows per block
#define KH 32     // K-half per thread
#define NT 512    // threads per block

__device__ __forceinline__ float sigm(float v){
  return __builtin_amdgcn_rcpf(1.f + __expf(-v));
}
__device__ __forceinline__ float tanh_(float v){
  return 1.f - 2.f*__builtin_amdgcn_rcpf(1.f + __expf(2.f*v));
}

__global__ __launch_bounds__(NT, 2)
void lstm2_head(const float* __restrict__ x,
                const float* __restrict__ Wih0, const float* __restrict__ Whh0,
                const float* __restrict__ bih0, const float* __restrict__ bhh0,
                const float* __restrict__ Wih1, const float* __restrict__ Whh1,
                const float* __restrict__ bih1, const float* __restrict__ bhh1,
                const float* __restrict__ W1, const float* __restrict__ b1,
                const float* __restrict__ W2, const float* __restrict__ b2,
                float* __restrict__ out)
{
  __shared__ __align__(16) float xs[BB][Tt*Dd];     // 48 KB
  __shared__ __align__(16) float h0s[BB][Hh];       // 1 KB
  __shared__ __align__(16) float h1s[BB][Hh];       // 1 KB
  __shared__ __align__(16) float act0[BB][4][Hh];   // 4 KB  (i,f,g,o)
  __shared__ __align__(16) float act1[BB][4][Hh];   // 4 KB
  __shared__ float zs[BB][32];

  const int tid  = threadIdx.x;
  const int half = tid & 1;        // K-half owner
  const int g    = tid >> 1;       // gate row 0..255 (shared by lane pair)
  const int gt   = g >> 6;         // gate type i,f,g,o
  const int gj   = g & 63;
  const int koff = half * KH;
  const int ulay = tid >> 8;       // cell-state mapping: layer
  const int ubs  = (tid >> 6) & 3; //   batch row
  const int uj   = tid & 63;       //   hidden index
  const int b0   = blockIdx.x * BB;

  // stage x (coalesced)
  {
    const float* gx = x + (size_t)b0 * (Tt*Dd);
    float* xf = &xs[0][0];
    for (int i = tid; i < BB*Tt*Dd; i += NT) xf[i] = gx[i];
  }
  // zero h state (512 floats, 512 threads)
  if (tid < BB*Hh) (&h0s[0][0])[tid] = 0.f;
  else             (&h1s[0][0])[tid - BB*Hh] = 0.f;

  // per-thread weights: half a gate row of each recurrent matrix (96 floats)
  float whh0r[KH], wih1r[KH], whh1r[KH];
  {
    const float4* p0 = (const float4*)&Whh0[g*Hh + koff];
    const float4* p1 = (const float4*)&Wih1[g*Hh + koff];
    const float4* p2 = (const float4*)&Whh1[g*Hh + koff];
    #pragma unroll
    for (int k = 0; k < KH/4; ++k){
      float4 v0 = p0[k], v1 = p1[k], v2 = p2[k];
      whh0r[4*k+0]=v0.x; whh0r[4*k+1]=v0.y; whh0r[4*k+2]=v0.z; whh0r[4*k+3]=v0.w;
      wih1r[4*k+0]=v1.x; wih1r[4*k+1]=v1.y; wih1r[4*k+2]=v1.z; wih1r[4*k+3]=v1.w;
      whh1r[4*k+0]=v2.x; whh1r[4*k+1]=v2.y; whh1r[4*k+2]=v2.z; whh1r[4*k+3]=v2.w;
    }
  }
  float wih0r[Dd];                 // x-projection row (used by odd lane)
  #pragma unroll
  for (int d = 0; d < Dd; ++d) wih0r[d] = Wih0[g*Dd + d];
  const float bias0 = bih0[g] + bhh0[g];
  const float bias1 = bih1[g] + bhh1[g];

  float creg = 0.f;                // cell state for (ulay, ubs, uj)

  __syncthreads();

  // prologue: act0(0) = act(bias0 + Wih0·x(0))  (h0(-1)=0) — odd lanes
  if (half == 1){
    #pragma unroll
    for (int bs = 0; bs < BB; ++bs){
      float acc = bias0;
      #pragma unroll
      for (int d = 0; d < Dd; ++d) acc += wih0r[d]*xs[bs][d];
      act0[bs][gt][gj] = (gt==2) ? tanh_(acc) : sigm(acc);
    }
  }
  __syncthreads();
  if (ulay == 0){
    float iv = act0[ubs][0][uj], fv = act0[ubs][1][uj],
          gv = act0[ubs][2][uj], ov = act0[ubs][3][uj];
    creg = fv*creg + iv*gv;
    h0s[ubs][uj] = ov * tanh_(creg);
  }
  __syncthreads();

  // steady state: entering iter t: h0s = h0(t), h1s = h1(t-1)
  #pragma unroll 1
  for (int t = 0; t < Tt; ++t){
    const bool withA = (t + 1 < Tt);

    float a0[BB], a1[BB];
    #pragma unroll
    for (int bs = 0; bs < BB; ++bs){ a0[bs] = 0.f; a1[bs] = 0.f; }

    #pragma unroll
    for (int jj = 0; jj < KH; jj += 4){
      #pragma unroll
      for (int bs = 0; bs < BB; ++bs){
        const float4 h0v = *(const float4*)&h0s[bs][koff + jj];  // 2-addr broadcast
        const float4 h1v = *(const float4*)&h1s[bs][koff + jj];
        a1[bs] += wih1r[jj+0]*h0v.x + wih1r[jj+1]*h0v.y
                + wih1r[jj+2]*h0v.z + wih1r[jj+3]*h0v.w;
        a1[bs] += whh1r[jj+0]*h1v.x + whh1r[jj+1]*h1v.y
                + whh1r[jj+2]*h1v.z + whh1r[jj+3]*h1v.w;
        a0[bs] += whh0r[jj+0]*h0v.x + whh0r[jj+1]*h0v.y
                + whh0r[jj+2]*h0v.z + whh0r[jj+3]*h0v.w;
      }
    }
    // pair-reduce: both lanes end with the full 64-K dot
    #pragma unroll
    for (int bs = 0; bs < BB; ++bs){
      a1[bs] += __shfl_xor(a1[bs], 1);
      a0[bs] += __shfl_xor(a0[bs], 1);
    }

    if (half == 0){                 // even lane: layer-1 gates
      #pragma unroll
      for (int bs = 0; bs < BB; ++bs){
        float v = a1[bs] + bias1;
        act1[bs][gt][gj] = (gt==2) ? tanh_(v) : sigm(v);
      }
    } else if (withA){              // odd lane: layer-0 gates for t+1
      #pragma unroll
      for (int bs = 0; bs < BB; ++bs){
        float xp = bias0;
        #pragma unroll
        for (int d = 0; d < Dd; ++d) xp += wih0r[d]*xs[bs][(t+1)*Dd + d];
        float v = a0[bs] + xp;
        act0[bs][gt][gj] = (gt==2) ? tanh_(v) : sigm(v);
      }
    }
    __syncthreads();

    if (ulay == 1){
      float iv = act1[ubs][0][uj], fv = act1[ubs][1][uj],
            gv = act1[ubs][2][uj], ov = act1[ubs][3][uj];
      creg = fv*creg + iv*gv;
      h1s[ubs][uj] = ov * tanh_(creg);
    } else if (withA){
      float iv = act0[ubs][0][uj], fv = act0[ubs][1][uj],
            gv = act0[ubs][2][uj], ov = act0[ubs][3][uj];
      creg = fv*creg + iv*gv;
      h0s[ubs][uj] = ov * tanh_(creg);
    }
    __syncthreads();
  }

  // MLP head: z = relu(h1 @ W1.T + b1); out = sigm(z @ W2.T + b2)
  if (tid < BB*32){
    const int bs = tid >> 5, m = tid & 31;
    float acc = b1[m];
    #pragma unroll
    for (int j = 0; j < Hh; ++j) acc += W1[m*Hh + j] * h1s[bs][j];
    zs[bs][m] = fmaxf(acc, 0.f);
  }
  __syncthreads();
  if (tid < BB){
    float acc = b2[0];
    #pragma unroll
    for (int m = 0; m < 32; ++m) acc += W2[m] * zs[tid][m];
    out[b0 + tid] = sigm(acc);
  }
}

extern "C" void kernel_launch(void* const* d_in, const int* in_sizes, int n_in,
                              void* d_out, int out_size, void* d_ws, size_t ws_size,
                              hipStream_t stream) {
  const float* x    = (const float*)d_in[0];
  const float* Wih0 = (const float*)d_in[1];
  const float* Whh0 = (const float*)d_in[2];
  const float* bih0 = (const float*)d_in[3];
  const float* bhh0 = (const float*)d_in[4];
  const float* Wih1 = (const float*)d_in[5];
  const float* Whh1 = (const float*)d_in[6];
  const float* bih1 = (const float*)d_in[7];
  const float* bhh1 = (const float*)d_in[8];
  const float* W1   = (const float*)d_in[9];
  const float* b1   = (const float*)d_in[10];
  const float* W2   = (const float*)d_in[11];
  const float* b2   = (const float*)d_in[12];

  const int B = in_sizes[0] / (Tt*Dd);   // 1024
  dim3 grid(B / BB), block(NT);
  hipLaunchKernelGGL(lstm2_head, grid, block, 0, stream,
                     x, Wih0, Whh0, bih0, bhh0, Wih1, Whh1, bih1, bhh1,
                     W1, b1, W2, b2, (float*)d_out);
}

// Round 3
// 567.909 us; speedup vs baseline: 18.5575x; 2.4465x over previous
//
#include <hip/hip_runtime.h>
#include <cstdint>

#define Hh 64
#define Tt 512
#define Dd 6
#define BB 4      // batch rows per block
#define NT 512    // threads per block (8 waves)

typedef short bf16x8 __attribute__((ext_vector_type(8)));
typedef float f32x4  __attribute__((ext_vector_type(4)));

#define MF(A, B, C) C = __builtin_amdgcn_mfma_f32_16x16x32_bf16(A, B, C, 0, 0, 0)

__device__ __forceinline__ float sigm(float v){
  return __builtin_amdgcn_rcpf(1.f + __expf(-v));
}
__device__ __forceinline__ float tanh_(float v){
  return 1.f - 2.f*__builtin_amdgcn_rcpf(1.f + __expf(2.f*v));
}
__device__ __forceinline__ unsigned short f2bf(float f){
  union { float f; unsigned u; } v; v.f = f;
  unsigned r = v.u + 0x7FFFu + ((v.u >> 16) & 1u);   // RNE
  return (unsigned short)(r >> 16);
}
__device__ __forceinline__ float bf2f(unsigned short b){
  union { unsigned u; float f; } v; v.u = ((unsigned)b) << 16;
  return v.f;
}
__device__ __forceinline__ void split8(const float* w, bf16x8& hi, bf16x8& lo){
  #pragma unroll
  for (int i = 0; i < 8; ++i){
    unsigned short h_ = f2bf(w[i]);
    hi[i] = (short)h_;
    lo[i] = (short)f2bf(w[i] - bf2f(h_));
  }
}

// LDS h-stage: 4 arrays (h0hi,h0lo,h1hi,h1lo), each [16 rows(n)][64 (j)] bf16,
// XOR-swizzled: byte = (n*128 + j*2) ^ ((n&7)<<4). Rows 4..15 stay zero.
__global__ __launch_bounds__(NT, 2)
void lstm2_mfma(const float* __restrict__ x,
                const float* __restrict__ Wih0, const float* __restrict__ Whh0,
                const float* __restrict__ bih0, const float* __restrict__ bhh0,
                const float* __restrict__ Wih1, const float* __restrict__ Whh1,
                const float* __restrict__ bih1, const float* __restrict__ bhh1,
                const float* __restrict__ W1, const float* __restrict__ b1,
                const float* __restrict__ W2, const float* __restrict__ b2,
                float* __restrict__ out)
{
  __shared__ __align__(16) float xs[BB*Tt*Dd];   // 48 KB
  __shared__ __align__(16) short hst[4*16*64];   // 8 KB
  __shared__ __align__(16) float pre[2*256*5];   // 10 KB, stride-5 rows
  __shared__ __align__(16) float h1f[BB*Hh];     // 1 KB
  __shared__ float zs[BB*32];

  const int tid  = threadIdx.x;
  const int lane = tid & 63;
  const int wid  = tid >> 6;        // wave 0..7
  const int lr   = lane & 15;       // MFMA row-in-tile (A) / col n (B,C)
  const int lg   = lane >> 4;       // k-group
  const int ulay = tid >> 8;        // update mapping: layer
  const int ubs  = (tid >> 6) & 3;  //   batch row
  const int uj   = tid & 63;        //   hidden index
  const int b0   = blockIdx.x * BB;

  // stage x (coalesced float4)
  {
    const float4* gx = (const float4*)(x + (size_t)b0 * (Tt*Dd));
    float4* xf = (float4*)xs;
    #pragma unroll
    for (int i = 0; i < (BB*Tt*Dd/4)/NT; ++i)   // 6
      xf[tid + i*NT] = gx[tid + i*NT];
  }
  // zero h stage (so B cols n>=4 read 0, and h1(-1)=0)
  {
    int* hz = (int*)hst;
    #pragma unroll
    for (int i = 0; i < 4; ++i) hz[tid + i*NT] = 0;
  }

  // ---- resident A-fragments: W split to bf16 hi/lo ----
  // convention: frag elem i of lane-group lg covers k = kt*32 + lg*8 + i
  // (self-consistent between A and B builds -> correct regardless of HW k-perm)
  bf16x8 A0[2][2][2];       // [mt][kt][hi/lo]           Whh0
  bf16x8 A1[2][2][2][2];    // [mt][mat(ih/hh)][kt][hi/lo]
  #pragma unroll
  for (int mt = 0; mt < 2; ++mt){
    const int row = (2*wid + mt)*16 + lr;
    #pragma unroll
    for (int kt = 0; kt < 2; ++kt){
      const int off = row*64 + kt*32 + lg*8;
      float wbuf[8];
      *(float4*)&wbuf[0] = *(const float4*)&Whh0[off];
      *(float4*)&wbuf[4] = *(const float4*)&Whh0[off+4];
      split8(wbuf, A0[mt][kt][0], A0[mt][kt][1]);
      *(float4*)&wbuf[0] = *(const float4*)&Wih1[off];
      *(float4*)&wbuf[4] = *(const float4*)&Wih1[off+4];
      split8(wbuf, A1[mt][0][kt][0], A1[mt][0][kt][1]);
      *(float4*)&wbuf[0] = *(const float4*)&Whh1[off];
      *(float4*)&wbuf[4] = *(const float4*)&Whh1[off+4];
      split8(wbuf, A1[mt][1][kt][0], A1[mt][1][kt][1]);
    }
  }

  // per-cell constants for the update phase
  float bias_g[4], w0r[24];
  if (ulay == 0){
    #pragma unroll
    for (int gt = 0; gt < 4; ++gt){
      const int row = gt*64 + uj;
      bias_g[gt] = bih0[row] + bhh0[row];
      #pragma unroll
      for (int d = 0; d < Dd; ++d) w0r[gt*6+d] = Wih0[row*Dd + d];
    }
  } else {
    #pragma unroll
    for (int gt = 0; gt < 4; ++gt){
      const int row = gt*64 + uj;
      bias_g[gt] = bih1[row] + bhh1[row];
      #pragma unroll
      for (int d = 0; d < Dd; ++d) w0r[gt*6+d] = 0.f;
    }
  }

  // B-frag read offsets (swizzled), loop-invariant
  const int bbase = lr*128 + lg*16;
  const int boff0 = (bbase)      ^ ((lr & 7) << 4);
  const int boff1 = (bbase + 64) ^ ((lr & 7) << 4);
  // h write offset (swizzled)
  const int woff  = (ubs*128 + uj*2) ^ (ubs << 4);

  float creg = 0.f;
  __syncthreads();

  // prologue: h0(0) from x(0) only (h0(-1)=0)
  if (ulay == 0){
    float g4[4];
    #pragma unroll
    for (int gt = 0; gt < 4; ++gt){
      float a = bias_g[gt];
      #pragma unroll
      for (int d = 0; d < Dd; ++d) a += w0r[gt*6+d] * xs[ubs*(Tt*Dd) + d];
      g4[gt] = a;
    }
    float iv = sigm(g4[0]), fv = sigm(g4[1]), gv = tanh_(g4[2]), ov = sigm(g4[3]);
    creg = fv*creg + iv*gv;
    float hval = ov * tanh_(creg);
    unsigned short hh = f2bf(hval);
    unsigned short hl = f2bf(hval - bf2f(hh));
    char* hw = (char*)hst;
    *(short*)(hw + woff)        = (short)hh;
    *(short*)(hw + 2048 + woff) = (short)hl;
  }
  __syncthreads();

  // steady state: entering iter t: hst holds h0(t) and h1(t-1)
  #pragma unroll 1
  for (int t = 0; t < Tt; ++t){
    // ---- MFMA phase: pre1(t) = Wih1 h0(t) + Whh1 h1(t-1); pre0(t+1) = Whh0 h0(t)
    bf16x8 bh[4][2];   // [h0hi,h0lo,h1hi,h1lo][kt]
    {
      const char* hb = (const char*)hst;
      #pragma unroll
      for (int a = 0; a < 4; ++a){
        bh[a][0] = *(const bf16x8*)(hb + a*2048 + boff0);
        bh[a][1] = *(const bf16x8*)(hb + a*2048 + boff1);
      }
    }
    f32x4 ac0a = {0,0,0,0}, ac0b = {0,0,0,0}, ac1a = {0,0,0,0}, ac1b = {0,0,0,0};
    // L0 tiles: Whi*hhi + Whi*hlo + Wlo*hhi over 2 K-tiles
    MF(A0[0][0][0], bh[0][0], ac0a); MF(A0[0][1][0], bh[0][1], ac0a);
    MF(A0[0][0][0], bh[1][0], ac0a); MF(A0[0][1][0], bh[1][1], ac0a);
    MF(A0[0][0][1], bh[0][0], ac0a); MF(A0[0][1][1], bh[0][1], ac0a);
    MF(A0[1][0][0], bh[0][0], ac0b); MF(A0[1][1][0], bh[0][1], ac0b);
    MF(A0[1][0][0], bh[1][0], ac0b); MF(A0[1][1][0], bh[1][1], ac0b);
    MF(A0[1][0][1], bh[0][0], ac0b); MF(A0[1][1][1], bh[0][1], ac0b);
    // L1 tiles: Wih1 with h0, Whh1 with h1
    MF(A1[0][0][0][0], bh[0][0], ac1a); MF(A1[0][0][1][0], bh[0][1], ac1a);
    MF(A1[0][0][0][0], bh[1][0], ac1a); MF(A1[0][0][1][0], bh[1][1], ac1a);
    MF(A1[0][0][0][1], bh[0][0], ac1a); MF(A1[0][0][1][1], bh[0][1], ac1a);
    MF(A1[0][1][0][0], bh[2][0], ac1a); MF(A1[0][1][1][0], bh[2][1], ac1a);
    MF(A1[0][1][0][0], bh[3][0], ac1a); MF(A1[0][1][1][0], bh[3][1], ac1a);
    MF(A1[0][1][0][1], bh[2][0], ac1a); MF(A1[0][1][1][1], bh[2][1], ac1a);
    MF(A1[1][0][0][0], bh[0][0], ac1b); MF(A1[1][0][1][0], bh[0][1], ac1b);
    MF(A1[1][0][0][0], bh[1][0], ac1b); MF(A1[1][0][1][0], bh[1][1], ac1b);
    MF(A1[1][0][0][1], bh[0][0], ac1b); MF(A1[1][0][1][1], bh[0][1], ac1b);
    MF(A1[1][1][0][0], bh[2][0], ac1b); MF(A1[1][1][1][0], bh[2][1], ac1b);
    MF(A1[1][1][0][0], bh[3][0], ac1b); MF(A1[1][1][1][0], bh[3][1], ac1b);
    MF(A1[1][1][0][1], bh[2][0], ac1b); MF(A1[1][1][1][1], bh[2][1], ac1b);

    // write preacts: C layout col=lane&15 (=bs), row=(lane>>4)*4+reg [m89]
    if (lr < 4){
      const int r0 = (2*wid)*16   + lg*4;
      const int r1 = (2*wid+1)*16 + lg*4;
      #pragma unroll
      for (int rg = 0; rg < 4; ++rg){
        pre[(r0+rg)*5 + lr]        = ac0a[rg];
        pre[(r1+rg)*5 + lr]        = ac0b[rg];
        pre[1280 + (r0+rg)*5 + lr] = ac1a[rg];
        pre[1280 + (r1+rg)*5 + lr] = ac1b[rg];
      }
    }
    __syncthreads();

    // ---- update phase ----
    const bool withA = (t + 1 < Tt);
    if (ulay == 1){
      float pi = pre[1280 + (      uj)*5 + ubs] + bias_g[0];
      float pf = pre[1280 + ( 64 + uj)*5 + ubs] + bias_g[1];
      float pg = pre[1280 + (128 + uj)*5 + ubs] + bias_g[2];
      float po = pre[1280 + (192 + uj)*5 + ubs] + bias_g[3];
      float iv = sigm(pi), fv = sigm(pf), gv = tanh_(pg), ov = sigm(po);
      creg = fv*creg + iv*gv;
      float hval = ov * tanh_(creg);
      h1f[ubs*64 + uj] = hval;
      unsigned short hh = f2bf(hval);
      unsigned short hl = f2bf(hval - bf2f(hh));
      char* hw = (char*)hst;
      *(short*)(hw + 4096 + woff) = (short)hh;
      *(short*)(hw + 6144 + woff) = (short)hl;
    } else if (withA){
      float xv[Dd];
      #pragma unroll
      for (int d = 0; d < Dd; ++d) xv[d] = xs[ubs*(Tt*Dd) + (t+1)*Dd + d];
      float g4[4];
      #pragma unroll
      for (int gt = 0; gt < 4; ++gt){
        float a = bias_g[gt];
        #pragma unroll
        for (int d = 0; d < Dd; ++d) a += w0r[gt*6+d] * xv[d];
        g4[gt] = a;
      }
      float pi = pre[(      uj)*5 + ubs] + g4[0];
      float pf = pre[( 64 + uj)*5 + ubs] + g4[1];
      float pg = pre[(128 + uj)*5 + ubs] + g4[2];
      float po = pre[(192 + uj)*5 + ubs] + g4[3];
      float iv = sigm(pi), fv = sigm(pf), gv = tanh_(pg), ov = sigm(po);
      creg = fv*creg + iv*gv;
      float hval = ov * tanh_(creg);
      unsigned short hh = f2bf(hval);
      unsigned short hl = f2bf(hval - bf2f(hh));
      char* hw = (char*)hst;
      *(short*)(hw + woff)        = (short)hh;
      *(short*)(hw + 2048 + woff) = (short)hl;
    }
    __syncthreads();
  }

  // ---- MLP head on h1(T-1) ----
  if (tid < BB*32){
    const int bs = tid >> 5, m = tid & 31;
    float acc = b1[m];
    #pragma unroll
    for (int j = 0; j < Hh; ++j) acc += W1[m*Hh + j] * h1f[bs*64 + j];
    zs[bs*32 + m] = fmaxf(acc, 0.f);
  }
  __syncthreads();
  if (tid < BB){
    float acc = b2[0];
    #pragma unroll
    for (int m = 0; m < 32; ++m) acc += W2[m] * zs[tid*32 + m];
    out[b0 + tid] = sigm(acc);
  }
}

extern "C" void kernel_launch(void* const* d_in, const int* in_sizes, int n_in,
                              void* d_out, int out_size, void* d_ws, size_t ws_size,
                              hipStream_t stream) {
  const float* x    = (const float*)d_in[0];
  const float* Wih0 = (const float*)d_in[1];
  const float* Whh0 = (const float*)d_in[2];
  const float* bih0 = (const float*)d_in[3];
  const float* bhh0 = (const float*)d_in[4];
  const float* Wih1 = (const float*)d_in[5];
  const float* Whh1 = (const float*)d_in[6];
  const float* bih1 = (const float*)d_in[7];
  const float* bhh1 = (const float*)d_in[8];
  const float* W1   = (const float*)d_in[9];
  const float* b1   = (const float*)d_in[10];
  const float* W2   = (const float*)d_in[11];
  const float* b2   = (const float*)d_in[12];

  const int B = in_sizes[0] / (Tt*Dd);   // 1024
  dim3 grid(B / BB), block(NT);
  hipLaunchKernelGGL(lstm2_mfma, grid, block, 0, stream,
                     x, Wih0, Whh0, bih0, bhh0, Wih1, Whh1, bih1, bhh1,
                     W1, b1, W2, b2, (float*)d_out);
}

// Round 4
// 430.088 us; speedup vs baseline: 24.5042x; 1.3204x over previous
//
#include <hip/hip_runtime.h>
#include <cstdint>

#define Hh 64
#define Tt 512
#define Dd 6
#define BB 4      // batch rows per block
#define NT 512    // threads per block (8 waves)
#define XS_STRIDE 3080   // 3072 + 8 pad words (bank stagger per batch row)
#define PRE_W 784        // per-wave pre stride (words)
#define PRE_L 388        // per-layer stride
#define PRE_G 96         // per-gate stride
#define PRE_N 12         // per-col stride

typedef short bf16x8 __attribute__((ext_vector_type(8)));
typedef float f32x4  __attribute__((ext_vector_type(4)));

#define MF(A, B, C) C = __builtin_amdgcn_mfma_f32_16x16x32_bf16(A, B, C, 0, 0, 0)

__device__ __forceinline__ float sigm(float v){
  return __builtin_amdgcn_rcpf(1.f + __expf(-v));
}
__device__ __forceinline__ float tanh_(float v){
  return 1.f - 2.f*__builtin_amdgcn_rcpf(1.f + __expf(2.f*v));
}
__device__ __forceinline__ unsigned short f2bf(float f){
  union { float f; unsigned u; } v; v.f = f;
  unsigned r = v.u + 0x7FFFu + ((v.u >> 16) & 1u);   // RNE
  return (unsigned short)(r >> 16);
}
__device__ __forceinline__ float bf2f(unsigned short b){
  union { unsigned u; float f; } v; v.u = ((unsigned)b) << 16;
  return v.f;
}
__device__ __forceinline__ void split8(const float* w, bf16x8& hi, bf16x8& lo){
  #pragma unroll
  for (int i = 0; i < 8; ++i){
    unsigned short h_ = f2bf(w[i]);
    hi[i] = (short)h_;
    lo[i] = (short)f2bf(w[i] - bf2f(h_));
  }
}

// h stage: hsb[buf][layer] planes of [16 rows(n)][64 (j)] bf16, XOR-swizzled:
// byte = (n*128 + j*2) ^ ((n&7)<<4). Rows 0-3 = h_hi(bs), 4-7 = h_lo(bs), 8-15 zero.
__global__ __launch_bounds__(NT, 2)
void lstm2_mfma(const float* __restrict__ x,
                const float* __restrict__ Wih0, const float* __restrict__ Whh0,
                const float* __restrict__ bih0, const float* __restrict__ bhh0,
                const float* __restrict__ Wih1, const float* __restrict__ Whh1,
                const float* __restrict__ bih1, const float* __restrict__ bhh1,
                const float* __restrict__ W1, const float* __restrict__ b1,
                const float* __restrict__ W2, const float* __restrict__ b2,
                float* __restrict__ out)
{
  __shared__ __align__(16) float xs[BB*XS_STRIDE];   // ~49 KB
  __shared__ __align__(16) short hsb[2*2*1024];      // 8 KB  [buf][layer][16][64]
  __shared__ __align__(16) float pre[8*PRE_W];       // ~25 KB, per-wave private
  __shared__ __align__(16) float h1f[BB*Hh];
  __shared__ float zs[BB*32];

  const int tid  = threadIdx.x;
  const int lane = tid & 63;
  const int wid  = tid >> 6;        // wave 0..7
  const int lr   = lane & 15;       // MFMA A-row-in-tile / B,C col
  const int lg   = lane >> 4;       // k-group / C row-group
  const int l    = lane >> 5;       // update: layer (0/1)
  const int jj   = (lane >> 2) & 7; // update: local j
  const int bs   = lane & 3;        // update: batch row
  const int jglob= wid*8 + jj;      // update: global hidden index
  const int b0   = blockIdx.x * BB;

  // stage x (coalesced float4, per batch row due to padded stride)
  #pragma unroll
  for (int bb = 0; bb < BB; ++bb){
    const float4* src = (const float4*)(x + (size_t)(b0+bb)*(Tt*Dd));
    float4* dst = (float4*)(xs + bb*XS_STRIDE);
    for (int i = tid; i < (Tt*Dd)/4; i += NT) dst[i] = src[i];
  }
  // zero h stage (both buffers, both layers)
  {
    int* hz = (int*)hsb;
    hz[tid] = 0; hz[tid+NT] = 0; hz[tid+2*NT] = 0; hz[tid+3*NT] = 0;
  }

  // ---- resident A-fragments (bf16 hi/lo split) ----
  // Row mapping: wave w, tile p, lane-row lr -> M row (p*2+(lr>>3))*64 + w*8 + (lr&7)
  // => wave w's 2 tiles cover all 4 gates of cells j in [8w, 8w+8).
  // frag elem i of k-group lg covers k = kt*32 + lg*8 + i.
  bf16x8 A0[2][2][2];       // [tile][kt][hi/lo]            Whh0
  bf16x8 A1[2][2][2][2];    // [tile][mat ih/hh][kt][hi/lo]
  #pragma unroll
  for (int p = 0; p < 2; ++p){
    const int m = (p*2 + (lr>>3))*64 + wid*8 + (lr&7);
    #pragma unroll
    for (int kt = 0; kt < 2; ++kt){
      const int off = m*64 + kt*32 + lg*8;
      float wbuf[8];
      *(float4*)&wbuf[0] = *(const float4*)&Whh0[off];
      *(float4*)&wbuf[4] = *(const float4*)&Whh0[off+4];
      split8(wbuf, A0[p][kt][0], A0[p][kt][1]);
      *(float4*)&wbuf[0] = *(const float4*)&Wih1[off];
      *(float4*)&wbuf[4] = *(const float4*)&Wih1[off+4];
      split8(wbuf, A1[p][0][kt][0], A1[p][0][kt][1]);
      *(float4*)&wbuf[0] = *(const float4*)&Whh1[off];
      *(float4*)&wbuf[4] = *(const float4*)&Whh1[off+4];
      split8(wbuf, A1[p][1][kt][0], A1[p][1][kt][1]);
    }
  }

  // update-phase constants (cell = (l, bs, jglob))
  float bias_g[4], w0r[24];
  #pragma unroll
  for (int gt = 0; gt < 4; ++gt){
    const int row = gt*64 + jglob;
    if (l == 0){
      bias_g[gt] = bih0[row] + bhh0[row];
      #pragma unroll
      for (int d = 0; d < Dd; ++d) w0r[gt*6+d] = Wih0[row*Dd + d];
    } else {
      bias_g[gt] = bih1[row] + bhh1[row];
      #pragma unroll
      for (int d = 0; d < Dd; ++d) w0r[gt*6+d] = 0.f;
    }
  }

  // loop-invariant offsets
  const int boff0 = (lr*128 + lg*16)      ^ ((lr&7)<<4);   // B-frag kt=0
  const int boff1 = (lr*128 + 64 + lg*16) ^ ((lr&7)<<4);   // B-frag kt=1
  const int whi   = (bs*128     + jglob*2) ^ (bs<<4);      // h_hi write byte
  const int wlo   = ((bs+4)*128 + jglob*2) ^ ((bs+4)<<4);  // h_lo write byte
  float* preW = pre + wid*PRE_W;
  const int pwbase = lr*PRE_N + (lg&1)*4 + (lg>>1)*PRE_G;  // write base (lr<8)
  const float* prd = preW + l*PRE_L + jj;                  // read base

  float creg = 0.f;
  __syncthreads();

  // prologue: h0(0) = update(pre=0, x(0)) — layer-0 lanes only
  if (l == 0){
    const float2* xv2 = (const float2*)(xs + bs*XS_STRIDE);
    float2 xa = xv2[0], xb = xv2[1], xc = xv2[2];
    float s[4];
    #pragma unroll
    for (int gt = 0; gt < 4; ++gt)
      s[gt] = bias_g[gt] + w0r[gt*6+0]*xa.x + w0r[gt*6+1]*xa.y
            + w0r[gt*6+2]*xb.x + w0r[gt*6+3]*xb.y
            + w0r[gt*6+4]*xc.x + w0r[gt*6+5]*xc.y;
    float iv = sigm(s[0]), fv = sigm(s[1]), gv = tanh_(s[2]), ov = sigm(s[3]);
    creg = fv*creg + iv*gv;
    float hval = ov * tanh_(creg);
    unsigned short hh = f2bf(hval);
    unsigned short hl = f2bf(hval - bf2f(hh));
    char* hw = (char*)hsb;                 // buf0, layer0 plane
    *(short*)(hw + whi) = (short)hh;
    *(short*)(hw + wlo) = (short)hl;
  }
  __syncthreads();

  // steady state: at iter t, hsb[t&1] holds h0(t) (layer0) and h1(t-1) (layer1)
  #pragma unroll 1
  for (int t = 0; t < Tt; ++t){
    const int buf = t & 1;
    const char* hb = (const char*)hsb + buf*4096;
    bf16x8 b00 = *(const bf16x8*)(hb + boff0);          // h0 kt0
    bf16x8 b01 = *(const bf16x8*)(hb + boff1);          // h0 kt1
    bf16x8 b10 = *(const bf16x8*)(hb + 2048 + boff0);   // h1 kt0
    bf16x8 b11 = *(const bf16x8*)(hb + 2048 + boff1);   // h1 kt1

    f32x4 a00 = {0,0,0,0}, a01 = {0,0,0,0}, a10 = {0,0,0,0}, a11 = {0,0,0,0};
    // layer0: (Whi + Wlo) x [h0hi | h0lo]  (4 MFMA per tile)
    MF(A0[0][0][0], b00, a00); MF(A0[1][0][0], b00, a01);
    MF(A1[0][0][0][0], b00, a10); MF(A1[1][0][0][0], b00, a11);
    MF(A0[0][1][0], b01, a00); MF(A0[1][1][0], b01, a01);
    MF(A1[0][0][1][0], b01, a10); MF(A1[1][0][1][0], b01, a11);
    MF(A0[0][0][1], b00, a00); MF(A0[1][0][1], b00, a01);
    MF(A1[0][0][0][1], b00, a10); MF(A1[1][0][0][1], b00, a11);
    MF(A0[0][1][1], b01, a00); MF(A0[1][1][1], b01, a01);
    MF(A1[0][0][1][1], b01, a10); MF(A1[1][0][1][1], b01, a11);
    // layer1 recurrent: Whh1 x [h1hi | h1lo]
    MF(A1[0][1][0][0], b10, a10); MF(A1[1][1][0][0], b10, a11);
    MF(A1[0][1][1][0], b11, a10); MF(A1[1][1][1][0], b11, a11);
    MF(A1[0][1][0][1], b10, a10); MF(A1[1][1][0][1], b10, a11);
    MF(A1[0][1][1][1], b11, a10); MF(A1[1][1][1][1], b11, a11);

    // epilogue: wave-private pre write (4x ds_write_b128)
    if (lr < 8){
      *(f32x4*)(preW + pwbase)                   = a00;
      *(f32x4*)(preW + pwbase + 2*PRE_G)         = a01;
      *(f32x4*)(preW + pwbase + PRE_L)           = a10;
      *(f32x4*)(preW + pwbase + PRE_L + 2*PRE_G) = a11;
    }

    // update (same-wave data; no barrier needed between write and read)
    if ((l == 1) | (t+1 < Tt)){
      float s0 = prd[          bs*PRE_N] + prd[          (bs+4)*PRE_N];
      float s1 = prd[  PRE_G + bs*PRE_N] + prd[  PRE_G + (bs+4)*PRE_N];
      float s2 = prd[2*PRE_G + bs*PRE_N] + prd[2*PRE_G + (bs+4)*PRE_N];
      float s3 = prd[3*PRE_G + bs*PRE_N] + prd[3*PRE_G + (bs+4)*PRE_N];
      s0 += bias_g[0]; s1 += bias_g[1]; s2 += bias_g[2]; s3 += bias_g[3];
      if (l == 0){
        const float2* xv2 = (const float2*)(xs + bs*XS_STRIDE + (t+1)*Dd);
        float2 xa = xv2[0], xb = xv2[1], xc = xv2[2];
        s0 += w0r[ 0]*xa.x + w0r[ 1]*xa.y + w0r[ 2]*xb.x
            + w0r[ 3]*xb.y + w0r[ 4]*xc.x + w0r[ 5]*xc.y;
        s1 += w0r[ 6]*xa.x + w0r[ 7]*xa.y + w0r[ 8]*xb.x
            + w0r[ 9]*xb.y + w0r[10]*xc.x + w0r[11]*xc.y;
        s2 += w0r[12]*xa.x + w0r[13]*xa.y + w0r[14]*xb.x
            + w0r[15]*xb.y + w0r[16]*xc.x + w0r[17]*xc.y;
        s3 += w0r[18]*xa.x + w0r[19]*xa.y + w0r[20]*xb.x
            + w0r[21]*xb.y + w0r[22]*xc.x + w0r[23]*xc.y;
      }
      float iv = sigm(s0), fv = sigm(s1), gv = tanh_(s2), ov = sigm(s3);
      creg = fv*creg + iv*gv;
      float hval = ov * tanh_(creg);
      if ((l == 1) & (t == Tt-1)) h1f[bs*64 + jglob] = hval;
      unsigned short hh = f2bf(hval);
      unsigned short hl = f2bf(hval - bf2f(hh));
      char* hw = (char*)hsb + (buf^1)*4096 + l*2048;
      *(short*)(hw + whi) = (short)hh;
      *(short*)(hw + wlo) = (short)hl;
    }
    __syncthreads();   // the ONE barrier per step (h double-buffered)
  }

  // ---- MLP head on h1(T-1) ----
  if (tid < BB*32){
    const int bsh = tid >> 5, m = tid & 31;
    float acc = b1[m];
    #pragma unroll
    for (int j = 0; j < Hh; ++j) acc += W1[m*Hh + j] * h1f[bsh*64 + j];
    zs[bsh*32 + m] = fmaxf(acc, 0.f);
  }
  __syncthreads();
  if (tid < BB){
    float acc = b2[0];
    #pragma unroll
    for (int m = 0; m < 32; ++m) acc += W2[m] * zs[tid*32 + m];
    out[b0 + tid] = sigm(acc);
  }
}

extern "C" void kernel_launch(void* const* d_in, const int* in_sizes, int n_in,
                              void* d_out, int out_size, void* d_ws, size_t ws_size,
                              hipStream_t stream) {
  const float* x    = (const float*)d_in[0];
  const float* Wih0 = (const float*)d_in[1];
  const float* Whh0 = (const float*)d_in[2];
  const float* bih0 = (const float*)d_in[3];
  const float* bhh0 = (const float*)d_in[4];
  const float* Wih1 = (const float*)d_in[5];
  const float* Whh1 = (const float*)d_in[6];
  const float* bih1 = (const float*)d_in[7];
  const float* bhh1 = (const float*)d_in[8];
  const float* W1   = (const float*)d_in[9];
  const float* b1   = (const float*)d_in[10];
  const float* W2   = (const float*)d_in[11];
  const float* b2   = (const float*)d_in[12];

  const int B = in_sizes[0] / (Tt*Dd);   // 1024
  dim3 grid(B / BB), block(NT);
  hipLaunchKernelGGL(lstm2_mfma, grid, block, 0, stream,
                     x, Wih0, Whh0, bih0, bhh0, Wih1, Whh1, bih1, bhh1,
                     W1, b1, W2, b2, (float*)d_out);
}